// Round 4
// baseline (218.609 us; speedup 1.0000x reference)
//
#include <hip/hip_runtime.h>
#include <math.h>

// N=M=8192, d=64, P=64, N_FT=1024 -> folded k = 1..512, active band contiguous
#define N_SRC 8192
#define D_DIM 64
#define P_SL  64
#define KH    512
#define NBLK  256

// ws float offsets (header zeroed by host memset of 64 bytes)
#define WS_NM    0                       // norm_max (float bits, atomicMax as uint)
#define WS_KMINE 1                       // uint: max(513 - k) over active k
#define WS_KMAXE 2                       // uint: max k over active k
#define WS_BARC  3                       // barrier arrival counter
#define WS_BARG  4                       // barrier generation
#define WS_WL    16                      // dense folded weights, index k-1 [512]
#define WS_CS    (16 + KH)               // wk*C, wk*S per (p, kidx rel kmin): P*KH*2
#define WS_A     (WS_CS + P_SL*KH*2)     // UNSCALED projections of x: P*N
#define WS_B2    (WS_A + P_SL*N_SRC)     // UNSCALED projections of y: P*N

__device__ __forceinline__ void sincos2pi(float t, float& s, float& c) {
    // v_sin_f32 / v_cos_f32 take REVOLUTIONS; fract maps into valid range.
    float f = __builtin_amdgcn_fractf(t);
    s = __builtin_amdgcn_sinf(f);
    c = __builtin_amdgcn_cosf(f);
}

// Grid-wide sense barrier. Safe: 256 blocks <= 256 CUs, tiny footprint -> all
// blocks resident. Release: __threadfence before arrive. Acquire: AGENT-scope
// atomic (invalidates this CU's L1) before the closing __syncthreads.
__device__ __forceinline__ void grid_barrier(unsigned* cnt, unsigned* gen) {
    __syncthreads();
    if (threadIdx.x == 0) {
        __threadfence();
        unsigned g = __hip_atomic_load(gen, __ATOMIC_RELAXED, __HIP_MEMORY_SCOPE_AGENT);
        unsigned a = __hip_atomic_fetch_add(cnt, 1u, __ATOMIC_ACQ_REL, __HIP_MEMORY_SCOPE_AGENT);
        if (a == NBLK - 1u) {
            __hip_atomic_store(cnt, 0u, __ATOMIC_RELAXED, __HIP_MEMORY_SCOPE_AGENT);
            __hip_atomic_fetch_add(gen, 1u, __ATOMIC_RELEASE, __HIP_MEMORY_SCOPE_AGENT);
        } else {
            while (__hip_atomic_load(gen, __ATOMIC_ACQUIRE, __HIP_MEMORY_SCOPE_AGENT) == g)
                __builtin_amdgcn_s_sleep(2);
        }
    }
    __syncthreads();
}

__global__ __launch_bounds__(256, 1) void k_fused(const float* __restrict__ x,
                                                  const float* __restrict__ y,
                                                  const float* __restrict__ xw,
                                                  const float* __restrict__ scale,
                                                  const float* __restrict__ xis,
                                                  float* ws, float* __restrict__ out) {
    __shared__ float sC[64], sS[64], sred[128];
    const int tid = threadIdx.x, b = blockIdx.x;
    const int gtid = b * 256 + tid;
    unsigned* hdr = (unsigned*)ws;
    unsigned* cnt = hdr + WS_BARC;
    unsigned* gen = hdr + WS_BARG;

    // ---------- Phase A: norms + unscaled projections + zero CS ----------
    {
        int r = gtid & 16383;           // row id over [x; y]
        int q = gtid >> 14;             // slice quarter 0..3 (wave-uniform)
        const float* src = (r < N_SRC) ? (x + (size_t)r * D_DIM)
                                       : (y + (size_t)(r - N_SRC) * D_DIM);
        float4 row[16];
        const float4* rp = (const float4*)src;
#pragma unroll
        for (int j = 0; j < 16; ++j) row[j] = rp[j];
        if (q == 0) {
            float ss = 0.f;
#pragma unroll
            for (int j = 0; j < 16; ++j) {
                ss = fmaf(row[j].x, row[j].x, ss); ss = fmaf(row[j].y, row[j].y, ss);
                ss = fmaf(row[j].z, row[j].z, ss); ss = fmaf(row[j].w, row[j].w, ss);
            }
            float nm = sqrtf(ss);
            for (int o = 32; o; o >>= 1) nm = fmaxf(nm, __shfl_xor(nm, o, 64));
            if ((tid & 63) == 0) atomicMax(hdr + WS_NM, __float_as_uint(nm));
        }
        ws[WS_CS + gtid] = 0.f;         // 65536 CS floats == 65536 threads
        float* dst = ws + ((r < N_SRC) ? WS_A : WS_B2);
        int rr = (r < N_SRC) ? r : r - N_SRC;
        for (int pi = 0; pi < 16; ++pi) {
            int p = q * 16 + pi;
            const float4* xi = (const float4*)(xis + p * D_DIM);  // uniform -> s_load
            float acc = 0.f;
#pragma unroll
            for (int j = 0; j < 16; ++j) {
                float4 u = xi[j];
                acc = fmaf(row[j].x, u.x, acc); acc = fmaf(row[j].y, u.y, acc);
                acc = fmaf(row[j].z, u.z, acc); acc = fmaf(row[j].w, u.w, acc);
            }
            dst[(size_t)p * N_SRC + rr] = acc;   // unscaled; sf folded into fk later
        }
    }
    grid_barrier(cnt, gen);

    // ---------- Phase B: kft weights + band (f32 log-space, matches ref) ----------
    if (gtid < KH) {
        int k = gtid + 1;  // 1..512
        float nm = __uint_as_float(hdr[WS_NM]);
        float sfb = 0.3f / nm;
        float sr = scale[0] * sfb;
        float a = 19.7392088f * sr * sr;         // 2*pi^2*sigma^2
        float logv = 32.0f * logf(a) + 63.0f * logf((float)k)
                   - a * (float)k * (float)k - 78.0922235f;  // lgamma(32)
        float v = expf(logv);
        ws[WS_WL + k - 1] = ((k == KH) ? 1.0f : 2.0f) * v * (1.0f / (float)P_SL);
        if (v > 1e-10f) {   // tail below 1e-10 contributes <1e-6 to out
            atomicMax(hdr + WS_KMINE, (unsigned)(513 - k));
            atomicMax(hdr + WS_KMAXE, (unsigned)k);
        }
    }
    grid_barrier(cnt, gen);

    const int kmin = 513 - (int)hdr[WS_KMINE];
    const int kmax = (int)hdr[WS_KMAXE];
    const int kcnt = kmax - kmin + 1;   // expected ~50 -> single 64-lane chunk
    const float sf = 0.3f / __uint_as_float(hdr[WS_NM]);

    // ---------- Phase C: adjoint NDFT (lane = frequency, scalar point loads) ----------
    if (kcnt > 0) {
        int p = b & 63, sg = b >> 6;
        int lane = tid & 63;
        int wv = __builtin_amdgcn_readfirstlane(tid >> 6);
        const float* ap = ws + WS_A + (size_t)p * N_SRC;
        for (int kbase = 0; kbase < kcnt; kbase += 64) {
            __syncthreads();
            if (tid < 64) { sC[tid] = 0.f; sS[tid] = 0.f; }
            __syncthreads();
            float fk = (float)(kmin + kbase + lane) * sf;
            float ca = 0.f, sa = 0.f;
            for (int seg = 0; seg < 2; ++seg) {
                int base = (sg * 8 + wv * 2 + seg) * 256;
                const float* aseg = ap + base;   // wave-uniform -> s_load
                const float* wseg = xw + base;
                for (int j = 0; j < 256; ++j) {
                    float t = fk * aseg[j];
                    float s, c; sincos2pi(t, s, c);
                    float wj = wseg[j];
                    ca = fmaf(wj, c, ca);
                    sa = fmaf(wj, s, sa);
                }
            }
            atomicAdd(&sC[lane], ca);
            atomicAdd(&sS[lane], sa);
            __syncthreads();
            if (tid < 64 && kbase + tid < kcnt) {
                float wk = ws[WS_WL + kmin - 1 + kbase + tid];
                atomicAdd(ws + WS_CS + ((size_t)p * KH + kbase + tid) * 2 + 0, wk * sC[tid]);
                atomicAdd(ws + WS_CS + ((size_t)p * KH + kbase + tid) * 2 + 1, wk * sS[tid]);
            }
        }
    }
    grid_barrier(cnt, gen);

    // ---------- Phase D: forward recurrence, block owns 32 outputs ----------
    {
        int wv = tid >> 6, lane = tid & 63;
        int m  = b * 32 + (lane & 31);
        int pg = wv * 2 + (lane >> 5);   // 0..7, 8 slices each
        float sum = 0.f;
        if (kcnt > 0) {
            for (int pi = 0; pi < 8; ++pi) {
                int p = pg + pi * 8;
                float bm = ws[WS_B2 + (size_t)p * N_SRC + m] * sf;
                float s1, c1; sincos2pi(bm, s1, c1);             // step e^{2pi i b}
                float s, c;  sincos2pi(bm * (float)kmin, s, c);  // start at kmin
                const float2* cs = (const float2*)(ws + WS_CS) + (size_t)p * KH;
                for (int k = 0; k < kcnt; ++k) {
                    float2 qv = cs[k];   // half-wave-uniform broadcast load
                    sum = fmaf(qv.x, c, sum);
                    sum = fmaf(qv.y, s, sum);
                    float t  = s * s1;
                    float cn = fmaf(c, c1, -t);
                    s = fmaf(s, c1, c * s1);
                    c = cn;
                }
            }
        }
        sum += __shfl_xor(sum, 32, 64);
        if (lane < 32) sred[wv * 32 + lane] = sum;
        __syncthreads();
        if (tid < 32)
            out[b * 32 + tid] = sred[tid] + sred[32 + tid] + sred[64 + tid] + sred[96 + tid];
    }
}

extern "C" void kernel_launch(void* const* d_in, const int* in_sizes, int n_in,
                              void* d_out, int out_size, void* d_ws, size_t ws_size,
                              hipStream_t stream) {
    const float* x     = (const float*)d_in[0];
    const float* y     = (const float*)d_in[1];
    const float* xw    = (const float*)d_in[2];
    const float* scale = (const float*)d_in[3];
    const float* xis   = (const float*)d_in[4];
    float* ws  = (float*)d_ws;
    float* out = (float*)d_out;

    hipMemsetAsync(ws, 0, 64, stream);  // header: norm/band/barrier state
    k_fused<<<dim3(NBLK), dim3(256), 0, stream>>>(x, y, xw, scale, xis, ws, out);
}

// Round 5
// 106.529 us; speedup vs baseline: 2.0521x; 2.0521x over previous
//
#include <hip/hip_runtime.h>
#include <math.h>

// N=M=8192, d=64, P=64, N_FT=1024 -> folded k = 1..512, active band contiguous
#define N_SRC 8192
#define D_DIM 64
#define P_SL  64
#define KH    512

// ws float offsets. NO host memset: WS_NM uses int atomicMax (0xAAAAAAAA poison
// is negative int -> loses to any positive float bits); CS/out zeroed by kA.
#define WS_NM    0                       // norm_max as float bits, int atomicMax
#define WS_CS    16                      // wk*C, wk*S per (p, k-kmin): P*KH*2
#define WS_A     (WS_CS + P_SL*KH*2)     // UNSCALED projections of x: P*N
#define WS_B2    (WS_A + P_SL*N_SRC)     // UNSCALED projections of y: P*N

#define LOG_THRESH (-23.0259f)           // ln(1e-10): tail adds <1e-6 to out
#define LGAMMA32    78.0922236f
#define TWO_PI2     19.7392088f

__device__ __forceinline__ void sincos2pi(float t, float& s, float& c) {
    // v_sin_f32 / v_cos_f32 take REVOLUTIONS; fract maps into valid range.
    float f = __builtin_amdgcn_fractf(t);
    s = __builtin_amdgcn_sinf(f);
    c = __builtin_amdgcn_cosf(f);
}

// kA: row norms (int atomicMax), unscaled projections (8 slices/thread),
// inline zeroing of CS accumulators and out. grid 512 x 256.
__global__ __launch_bounds__(256) void kA(const float* __restrict__ x,
                                          const float* __restrict__ y,
                                          const float* __restrict__ xis,
                                          float* __restrict__ ws,
                                          float* __restrict__ out) {
    int tid = threadIdx.x, b = blockIdx.x;
    int rblk = b & 63, q = b >> 6;          // q in [0,8): slice eighth, block-uniform
    int r = rblk * 256 + tid;               // 0..16383 over [x; y]
    int isx = (r < N_SRC);
    const float* src = isx ? (x + (size_t)r * D_DIM)
                           : (y + (size_t)(r - N_SRC) * D_DIM);
    float4 row[16];
    const float4* rp = (const float4*)src;
#pragma unroll
    for (int j = 0; j < 16; ++j) row[j] = rp[j];

    if (q == 0) {  // 64 blocks cover all 16384 rows for the norm
        float ss = 0.f;
#pragma unroll
        for (int j = 0; j < 16; ++j) {
            ss = fmaf(row[j].x, row[j].x, ss); ss = fmaf(row[j].y, row[j].y, ss);
            ss = fmaf(row[j].z, row[j].z, ss); ss = fmaf(row[j].w, row[j].w, ss);
        }
        float nm = sqrtf(ss);
        for (int o = 32; o; o >>= 1) nm = fmaxf(nm, __shfl_xor(nm, o, 64));
        if ((tid & 63) == 0)
            atomicMax((int*)ws + WS_NM, __float_as_int(nm));
    }

    int gtid = b * 256 + tid;               // 0..131071
    if (gtid < P_SL * KH * 2) ws[WS_CS + gtid] = 0.f;
    if (gtid < N_SRC)         out[gtid] = 0.f;

    int rr = isx ? r : r - N_SRC;
    float* dst = ws + (isx ? WS_A : WS_B2);
    for (int pi = 0; pi < 8; ++pi) {
        int p = q * 8 + pi;
        const float4* xi = (const float4*)(xis + p * D_DIM);  // uniform -> s_load
        float acc = 0.f;
#pragma unroll
        for (int j = 0; j < 16; ++j) {
            float4 u = xi[j];
            acc = fmaf(row[j].x, u.x, acc); acc = fmaf(row[j].y, u.y, acc);
            acc = fmaf(row[j].z, u.z, acc); acc = fmaf(row[j].w, u.w, acc);
        }
        dst[(size_t)p * N_SRC + rr] = acc;  // unscaled; sf folded later
    }
}

// kB: adjoint NDFT. Band recomputed locally per block (deterministic).
// Lane = frequency; point data via wave-uniform loads. grid (16 chunks, 64 p).
__global__ __launch_bounds__(256) void kB(const float* __restrict__ xw,
                                          const float* __restrict__ scale,
                                          float* __restrict__ ws) {
    __shared__ int skmin, skmax;
    __shared__ float sC[64], sS[64];
    int tid = threadIdx.x;
    int chunk = blockIdx.x, p = blockIdx.y;
    if (tid == 0) { skmin = 0x7fffffff; skmax = 0; }
    __syncthreads();
    float nm = __int_as_float(((const int*)ws)[WS_NM]);
    float sf = 0.3f / nm;
    float sr = scale[0] * sf;
    float a = TWO_PI2 * sr * sr;            // 2*pi^2*sigma^2
    float la = logf(a);
    for (int k = tid + 1; k <= KH; k += 256) {
        float logv = 32.f * la + 63.f * logf((float)k)
                   - a * (float)k * (float)k - LGAMMA32;
        if (logv > LOG_THRESH) { atomicMin(&skmin, k); atomicMax(&skmax, k); }
    }
    __syncthreads();
    int kmin = skmin, kmax = skmax;
    if (kmax == 0) return;                  // block-uniform
    int kcnt = kmax - kmin + 1;             // ~50 expected; loop handles any
    int lane = tid & 63;
    int wv = __builtin_amdgcn_readfirstlane(tid >> 6);
    const float* ap = ws + WS_A + (size_t)p * N_SRC + chunk * 512 + wv * 128;
    const float* wp = xw + chunk * 512 + wv * 128;
    for (int kbase = 0; kbase < kcnt; kbase += 64) {
        __syncthreads();
        if (tid < 64) { sC[tid] = 0.f; sS[tid] = 0.f; }
        __syncthreads();
        float fk = (float)(kmin + kbase + lane) * sf;
        float ca = 0.f, sa = 0.f;
#pragma unroll 8
        for (int j = 0; j < 128; ++j) {     // wave-uniform addresses -> s_load
            float aj = ap[j], wj = wp[j];
            float t = fk * aj;
            float s, c; sincos2pi(t, s, c);
            ca = fmaf(wj, c, ca);
            sa = fmaf(wj, s, sa);
        }
        atomicAdd(&sC[lane], ca);
        atomicAdd(&sS[lane], sa);
        __syncthreads();
        int ki = kbase + tid;
        if (tid < 64 && ki < kcnt) {
            int kk = kmin + ki;
            float logv = 32.f * la + 63.f * logf((float)kk)
                       - a * (float)kk * (float)kk - LGAMMA32;
            float wk = ((kk == KH) ? 1.f : 2.f) * expf(logv) * (1.f / (float)P_SL);
            atomicAdd(ws + WS_CS + ((size_t)p * KH + ki) * 2 + 0, wk * sC[tid]);
            atomicAdd(ws + WS_CS + ((size_t)p * KH + ki) * 2 + 1, wk * sS[tid]);
        }
    }
}

// kC: forward NDFT, direct sincos (independent per k -> pipelined).
// grid (32 m-chunks, 16 p-groups of 4). One atomicAdd per (m, pgroup).
__global__ __launch_bounds__(256) void kC(const float* __restrict__ scale,
                                          float* __restrict__ ws,
                                          float* __restrict__ out) {
    __shared__ int skmin, skmax;
    int tid = threadIdx.x;
    if (tid == 0) { skmin = 0x7fffffff; skmax = 0; }
    __syncthreads();
    float nm = __int_as_float(((const int*)ws)[WS_NM]);
    float sf = 0.3f / nm;
    float sr = scale[0] * sf;
    float a = TWO_PI2 * sr * sr;
    float la = logf(a);
    for (int k = tid + 1; k <= KH; k += 256) {
        float logv = 32.f * la + 63.f * logf((float)k)
                   - a * (float)k * (float)k - LGAMMA32;
        if (logv > LOG_THRESH) { atomicMin(&skmin, k); atomicMax(&skmax, k); }
    }
    __syncthreads();
    int kmin = skmin, kmax = skmax;
    if (kmax == 0) return;                  // out already zeroed by kA
    int kcnt = kmax - kmin + 1;
    int m = blockIdx.x * 256 + tid;
    int pg = blockIdx.y;
    float sum = 0.f;
    for (int pi = 0; pi < 4; ++pi) {
        int p = pg * 4 + pi;
        float bm = ws[WS_B2 + (size_t)p * N_SRC + m] * sf;
        const float2* cs = (const float2*)(ws + WS_CS) + (size_t)p * KH;
#pragma unroll 4
        for (int i = 0; i < kcnt; ++i) {
            float2 q = cs[i];               // wave-uniform -> s_load
            float t = bm * (float)(kmin + i);
            float s, c; sincos2pi(t, s, c);
            sum = fmaf(q.x, c, sum);
            sum = fmaf(q.y, s, sum);
        }
    }
    atomicAdd(out + m, sum);
}

extern "C" void kernel_launch(void* const* d_in, const int* in_sizes, int n_in,
                              void* d_out, int out_size, void* d_ws, size_t ws_size,
                              hipStream_t stream) {
    const float* x     = (const float*)d_in[0];
    const float* y     = (const float*)d_in[1];
    const float* xw    = (const float*)d_in[2];
    const float* scale = (const float*)d_in[3];
    const float* xis   = (const float*)d_in[4];
    float* ws  = (float*)d_ws;
    float* out = (float*)d_out;

    kA<<<dim3(512),      dim3(256), 0, stream>>>(x, y, xis, ws, out);
    kB<<<dim3(16, 64),   dim3(256), 0, stream>>>(xw, scale, ws);
    kC<<<dim3(32, 16),   dim3(256), 0, stream>>>(scale, ws, out);
}